// Round 12
// baseline (129.283 us; speedup 1.0000x reference)
//
#include <hip/hip_runtime.h>
#include <hip/hip_bf16.h>

#define NN 50000
#define NE 400000
#define NET (NE + NN)
#define F1 512
#define SLOPE 0.2f
#define GEPS 1e-16f
#define BCAP 64                  // CSR bucket capacity (Poisson(9): P(deg>63) ~ 1e-35)

#define GEMM_BLKS 391            // ceil(50000/128)
#define SCAT_BLKS ((NET + 255) / 256)

typedef __attribute__((ext_vector_type(8))) short bf16x8;
typedef __attribute__((ext_vector_type(4))) float f32x4;
typedef __attribute__((ext_vector_type(2))) float f32x2;

// XOR-swizzle: row stride 256B; xor byte bits 4-6 with row bits 0-2 (T2)
#define SWZ(b) ((b) ^ ((((b) >> 8) & 7) << 4))

static __device__ __forceinline__ unsigned short f2b(float f) {
  __hip_bfloat16 b = __float2bfloat16(f);
  return __builtin_bit_cast(unsigned short, b);
}
static __device__ __forceinline__ float bitsf(unsigned u) {
  return __builtin_bit_cast(float, u);
}

// ---------------- prep: W1 transpose+cast (bf16) + cnt zero ----------------
__global__ __launch_bounds__(256) void prep_k(const float* __restrict__ W,
                                              unsigned short* __restrict__ wt,
                                              int* __restrict__ cnt) {
  const int i = blockIdx.x * 256 + threadIdx.x;
  if (i < F1 * 128) {
    const int n = i >> 7, k = i & 127;
    wt[i] = f2b(W[k * F1 + n]);
  }
  if (i < NN) cnt[i] = 0;
}

// ---------------- fused: MFMA GEMM (+x-cast +alpha dots) AND bucket-CSR scatter ----------------
// B fragments read directly from wt (L2-hot, 128 KB) — no B LDS staging, 32 KB LDS.
__global__ __launch_bounds__(256) void gemm_scat_k(const float* __restrict__ x,
                                                   const unsigned short* __restrict__ wt,
                                                   const float* __restrict__ a_src,
                                                   const float* __restrict__ a_dst,
                                                   __hip_bfloat16* __restrict__ h,
                                                   float* __restrict__ as1,
                                                   float* __restrict__ ad1,
                                                   const int* __restrict__ ei,
                                                   int* __restrict__ cnt,
                                                   int* __restrict__ csr) {
  const int t = threadIdx.x;

  if (blockIdx.x >= GEMM_BLKS) {  // ---- scatter part (bucketed, no offsets pass) ----
    const int e = (blockIdx.x - GEMM_BLKS) * 256 + t;
    if (e >= NET) return;
    int s, d;
    if (e < NE) { s = ei[e]; d = ei[NE + e]; }
    else        { s = e - NE; d = s; }
    if ((unsigned)d >= NN || (unsigned)s >= NN) return;
    const int pos = atomicAdd(&cnt[d], 1);
    if (pos < BCAP) csr[d * BCAP + pos] = s;
    return;
  }

  // ---- GEMM part ----
  __shared__ char lds[32768];  // A only: 128 rows x 256B
  const int m0 = blockIdx.x * 128;
  const int l16 = t & 15, g16 = t >> 4;

  // stage A once (cast fp32 -> bf16 in-register)
#pragma unroll
  for (int p = 0; p < 8; ++p) {
    const int row = p * 16 + g16;
    const int gm = m0 + row;
    bf16x8 av = {};
    if (gm < NN) {
      const float4 f0 = *(const float4*)(x + (size_t)gm * 128 + l16 * 8);
      const float4 f1 = *(const float4*)(x + (size_t)gm * 128 + l16 * 8 + 4);
      av[0] = f2b(f0.x); av[1] = f2b(f0.y); av[2] = f2b(f0.z); av[3] = f2b(f0.w);
      av[4] = f2b(f1.x); av[5] = f2b(f1.y); av[6] = f2b(f1.z); av[7] = f2b(f1.w);
    }
    *(bf16x8*)(lds + SWZ(row * 256 + l16 * 16)) = av;
  }
  __syncthreads();  // the only barrier: A is read-only hereafter

  const int w = t >> 6;
  const int lane = t & 63;
  const int lrow = lane & 15;
  const int kgrp = (lane >> 4) * 8;     // k-offset (ushorts) within 32-k slice
  const int rbase = (lane >> 4) * 4;

  for (int nt = 0; nt < 4; ++nt) {
    const int n0 = nt * 128;

    f32x4 acc[2][8] = {};
#pragma unroll
    for (int ks = 0; ks < 4; ++ks) {
      const int kb = (ks * 32 + kgrp) * 2;        // byte offset for A LDS read
      const int ku = ks * 32 + kgrp;              // ushort offset for B global read
      bf16x8 a[2], b[8];
#pragma unroll
      for (int mr = 0; mr < 2; ++mr) {
        const int row = w * 32 + mr * 16 + lrow;
        a[mr] = *(const bf16x8*)(lds + SWZ(row * 256 + kb));
      }
#pragma unroll
      for (int nr = 0; nr < 8; ++nr) {
        const int rowb = n0 + nr * 16 + lrow;     // global wt row (n index)
        b[nr] = *(const bf16x8*)(wt + (size_t)rowb * 128 + ku);
      }
#pragma unroll
      for (int mr = 0; mr < 2; ++mr)
#pragma unroll
        for (int nr = 0; nr < 8; ++nr)
          acc[mr][nr] = __builtin_amdgcn_mfma_f32_16x16x32_bf16(a[mr], b[nr], acc[mr][nr], 0, 0, 0);
    }

    // epilogue for this n-tile: store h (bf16) + per-head alpha dots (fp32)
    const int head0 = n0 >> 6;
    float asv[8], adv[8];
#pragma unroll
    for (int nr = 0; nr < 8; ++nr) {
      const int cwh = (nr & 3) * 16 + lrow;
      asv[nr] = a_src[(head0 + (nr >> 2)) * 64 + cwh];
      adv[nr] = a_dst[(head0 + (nr >> 2)) * 64 + cwh];
    }
#pragma unroll
    for (int mr = 0; mr < 2; ++mr) {
#pragma unroll
      for (int r = 0; r < 4; ++r) {
        const int grow = m0 + w * 32 + mr * 16 + rbase + r;
        if (grow >= NN) continue;  // uniform within each 16-lane group
        float s0 = 0.f, s1 = 0.f, d0 = 0.f, d1 = 0.f;
#pragma unroll
        for (int nr = 0; nr < 8; ++nr) {
          const float v = acc[mr][nr][r];
          h[(size_t)grow * F1 + n0 + nr * 16 + lrow] = __float2bfloat16(v);
          if (nr < 4) { s0 = fmaf(v, asv[nr], s0); d0 = fmaf(v, adv[nr], d0); }
          else        { s1 = fmaf(v, asv[nr], s1); d1 = fmaf(v, adv[nr], d1); }
        }
#pragma unroll
        for (int m = 1; m < 16; m <<= 1) {
          s0 += __shfl_xor(s0, m); s1 += __shfl_xor(s1, m);
          d0 += __shfl_xor(d0, m); d1 += __shfl_xor(d1, m);
        }
        if (lrow == 0) {
          as1[grow * 8 + head0] = s0; as1[grow * 8 + head0 + 1] = s1;
          ad1[grow * 8 + head0] = d0; ad1[grow * 8 + head0 + 1] = d1;
        }
      }
    }
  }
}

// ---------------- layer-1 aggregate + ReLU + layer-2 projection fused ----------------
// R9 winner: 1 wave per node, 256-thread blocks, bucket CSR, 2x4 software pipeline.
__global__ __launch_bounds__(256) void agg1_k(const __hip_bfloat16* __restrict__ h,
                                              const float* __restrict__ as1,
                                              const float* __restrict__ ad1,
                                              const float* __restrict__ b1,
                                              const int* __restrict__ cnt,
                                              const int* __restrict__ csr,
                                              const float* __restrict__ W2,
                                              const float* __restrict__ a_s2,
                                              const float* __restrict__ a_d2,
                                              float* __restrict__ g,
                                              float* __restrict__ s2,
                                              float* __restrict__ d2) {
  const int gid = blockIdx.x * 256 + threadIdx.x;
  // node is wave-uniform; readfirstlane lets the compiler scalarize cnt/csr loads
  const int node = __builtin_amdgcn_readfirstlane(gid >> 6);
  if (node >= NN) return;
  const int lane = threadIdx.x & 63;
  const int head = lane >> 3;
  const float adv = ad1[node * 8 + head];
  int degn = cnt[node];
  degn = (degn > BCAP) ? BCAP : degn;
  const int cbase = node * BCAP;
  const unsigned short* hp = (const unsigned short*)h;
  const unsigned loff = (unsigned)(lane * 8);

  f32x2 acc2[4] = {};   // channels (2i, 2i+1) of this lane's 8
  float den = 0.f;

#define LOADC(ss, hh, aa)                                              \
  hh = *(const bf16x8*)(hp + (unsigned)(ss) * (unsigned)F1 + loff);    \
  aa = as1[(ss) * 8 + head];

#define CONSUME(hh, aa)                                                \
  {                                                                    \
    float ev = (aa) + adv;                                             \
    ev = (ev > 0.f) ? ev : ev * SLOPE;                                 \
    const float pe = __expf(ev);                                       \
    den += pe;                                                         \
    const f32x2 pv = {pe, pe};                                         \
    const unsigned* hu = (const unsigned*)&(hh);                       \
    _Pragma("unroll")                                                  \
    for (int i = 0; i < 4; ++i) {                                      \
      const unsigned u = hu[i];                                        \
      const f32x2 hv2 = {bitsf(u << 16), bitsf(u & 0xffff0000u)};      \
      acc2[i] = __builtin_elementwise_fma(pv, hv2, acc2[i]);           \
    }                                                                  \
  }

  int idx = 0;
  const bool have = (idx + 4 <= degn);
  bf16x8 hA = {}, hB = {}, hC = {}, hD = {};
  float aA = 0.f, aB = 0.f, aC = 0.f, aD = 0.f;
  if (have) {
    const int cA = csr[cbase], cB = csr[cbase + 1], cC = csr[cbase + 2], cD = csr[cbase + 3];
    LOADC(cA, hA, aA); LOADC(cB, hB, aB); LOADC(cC, hC, aC); LOADC(cD, hD, aD);
  }
  for (; idx + 8 <= degn; idx += 4) {
    // issue next chunk's loads first (overlaps with current chunk's math)
    const int nA = csr[cbase + idx + 4], nB = csr[cbase + idx + 5];
    const int nC = csr[cbase + idx + 6], nD = csr[cbase + idx + 7];
    bf16x8 xA, xB, xC, xD;
    float yA, yB, yC, yD;
    LOADC(nA, xA, yA); LOADC(nB, xB, yB); LOADC(nC, xC, yC); LOADC(nD, xD, yD);
    CONSUME(hA, aA); CONSUME(hB, aB); CONSUME(hC, aC); CONSUME(hD, aD);
    hA = xA; hB = xB; hC = xC; hD = xD;
    aA = yA; aB = yB; aC = yC; aD = yD;
  }
  if (have) {
    CONSUME(hA, aA); CONSUME(hB, aB); CONSUME(hC, aC); CONSUME(hD, aD);
    idx += 4;
  }
  for (; idx < degn; ++idx) {
    const int s = csr[cbase + idx];
    bf16x8 hv; float av;
    LOADC(s, hv, av);
    CONSUME(hv, av);
  }
#undef LOADC
#undef CONSUME

  const float inv = 1.f / (den + GEPS);
  float g0 = 0.f, g1 = 0.f;
#pragma unroll
  for (int i = 0; i < 4; ++i) {
#pragma unroll
    for (int k = 0; k < 2; ++k) {
      const int c = lane * 8 + 2 * i + k;
      const float v = fmaxf(fmaf(k ? acc2[i].y : acc2[i].x, inv, b1[c]), 0.f);
      g0 = fmaf(v, W2[2 * c + 0], g0);
      g1 = fmaf(v, W2[2 * c + 1], g1);
    }
  }
#pragma unroll
  for (int m = 1; m < 64; m <<= 1) {
    g0 += __shfl_xor(g0, m);
    g1 += __shfl_xor(g1, m);
  }
  if (lane == 0) {
    g[node * 2 + 0] = g0;
    g[node * 2 + 1] = g1;
    s2[node] = g0 * a_s2[0] + g1 * a_s2[1];
    d2[node] = g0 * a_d2[0] + g1 * a_d2[1];
  }
}

// ---------------- layer-2 aggregate (8 lanes per node) ----------------
__global__ __launch_bounds__(256) void agg2_k(const float* __restrict__ g,
                                              const float* __restrict__ s2,
                                              const float* __restrict__ d2,
                                              const float* __restrict__ b2,
                                              const int* __restrict__ cnt,
                                              const int* __restrict__ csr,
                                              float* __restrict__ out) {
  const int gid = blockIdx.x * 256 + threadIdx.x;
  const int node = gid >> 3;
  if (node >= NN) return;
  const int sub = threadIdx.x & 7;
  const float adv = d2[node];
  int degn = cnt[node];
  degn = (degn > BCAP) ? BCAP : degn;
  const int cbase = node * BCAP;
  float den = 0.f, a0 = 0.f, a1 = 0.f;
  int idx = sub;
  for (; idx + 8 < degn; idx += 16) {
    const int sA = csr[cbase + idx];
    const int sB = csr[cbase + idx + 8];
    const float2 gA = *(const float2*)(g + 2 * sA);
    const float2 gB = *(const float2*)(g + 2 * sB);
    float eA = s2[sA] + adv; eA = (eA > 0.f) ? eA : eA * SLOPE;
    float eB = s2[sB] + adv; eB = (eB > 0.f) ? eB : eB * SLOPE;
    const float pA = __expf(eA);
    const float pB = __expf(eB);
    den += pA + pB;
    a0 = fmaf(pA, gA.x, a0); a1 = fmaf(pA, gA.y, a1);
    a0 = fmaf(pB, gB.x, a0); a1 = fmaf(pB, gB.y, a1);
  }
  if (idx < degn) {
    const int s = csr[cbase + idx];
    const float2 gv = *(const float2*)(g + 2 * s);
    float ev = s2[s] + adv;
    ev = (ev > 0.f) ? ev : ev * SLOPE;
    const float p = __expf(ev);
    den += p;
    a0 = fmaf(p, gv.x, a0); a1 = fmaf(p, gv.y, a1);
  }
#pragma unroll
  for (int m = 1; m < 8; m <<= 1) {
    den += __shfl_xor(den, m);
    a0 += __shfl_xor(a0, m);
    a1 += __shfl_xor(a1, m);
  }
  if (sub == 0) {
    const float inv = 1.f / (den + GEPS);
    out[2 * node + 0] = a0 * inv + b2[0];
    out[2 * node + 1] = a1 * inv + b2[1];
  }
}

extern "C" void kernel_launch(void* const* d_in, const int* in_sizes, int n_in,
                              void* d_out, int out_size, void* d_ws, size_t ws_size,
                              hipStream_t stream) {
  (void)in_sizes; (void)n_in; (void)out_size; (void)ws_size;
  const float* x = (const float*)d_in[0];
  const int* ei = (const int*)d_in[1];
  const float* W1 = (const float*)d_in[2];
  const float* a_src1 = (const float*)d_in[3];
  const float* a_dst1 = (const float*)d_in[4];
  const float* b1 = (const float*)d_in[5];
  const float* W2 = (const float*)d_in[6];
  const float* a_src2 = (const float*)d_in[7];
  const float* a_dst2 = (const float*)d_in[8];
  const float* b2 = (const float*)d_in[9];
  float* out = (float*)d_out;

  char* ws = (char*)d_ws;
  auto alloc = [&](size_t bytes) { char* p = ws; ws += (bytes + 255) & ~(size_t)255; return p; };
  __hip_bfloat16* h = (__hip_bfloat16*)alloc((size_t)NN * F1 * 2);  // 51.2 MB
  unsigned short* wt = (unsigned short*)alloc((size_t)F1 * 128 * 2);
  float* as1 = (float*)alloc((size_t)NN * 8 * 4);
  float* ad1 = (float*)alloc((size_t)NN * 8 * 4);
  int* cnt = (int*)alloc((size_t)NN * 4);
  int* csr = (int*)alloc((size_t)NN * BCAP * 4);  // 12.8 MB buckets
  float* g = (float*)alloc((size_t)NN * 2 * 4);
  float* s2 = (float*)alloc((size_t)NN * 4);
  float* d2 = (float*)alloc((size_t)NN * 4);

  prep_k<<<(F1 * 128 + 255) / 256, 256, 0, stream>>>(W1, wt, cnt);  // also zeroes cnt
  gemm_scat_k<<<GEMM_BLKS + SCAT_BLKS, 256, 0, stream>>>(x, wt, a_src1, a_dst1, h, as1, ad1,
                                                         ei, cnt, csr);
  agg1_k<<<(NN * 64) / 256, 256, 0, stream>>>(h, as1, ad1, b1, cnt, csr, W2, a_src2, a_dst2, g, s2, d2);
  agg2_k<<<(NN * 8 + 255) / 256, 256, 0, stream>>>(g, s2, d2, b2, cnt, csr, out);
}

// Round 13
// 114.229 us; speedup vs baseline: 1.1318x; 1.1318x over previous
//
#include <hip/hip_runtime.h>
#include <hip/hip_bf16.h>

#define NN 50000
#define NE 400000
#define NET (NE + NN)
#define F1 512
#define SLOPE 0.2f
#define GEPS 1e-16f
#define BCAP 64                  // CSR bucket capacity (Poisson(9): P(deg>63) ~ 1e-35)

#define GEMM_BLKS 391            // ceil(50000/128)
#define SCAT_BLKS ((NET + 255) / 256)

typedef __attribute__((ext_vector_type(8))) short bf16x8;
typedef __attribute__((ext_vector_type(4))) float f32x4;
typedef __attribute__((ext_vector_type(2))) float f32x2;

// XOR-swizzle: row stride 256B; xor byte bits 4-6 with row bits 0-2 (T2)
#define SWZ(b) ((b) ^ ((((b) >> 8) & 7) << 4))

static __device__ __forceinline__ unsigned short f2b(float f) {
  __hip_bfloat16 b = __float2bfloat16(f);
  return __builtin_bit_cast(unsigned short, b);
}
static __device__ __forceinline__ float bitsf(unsigned u) {
  return __builtin_bit_cast(float, u);
}

// ---------------- prep: W1 transpose+cast (bf16) + cnt zero ----------------
__global__ __launch_bounds__(256) void prep_k(const float* __restrict__ W,
                                              unsigned short* __restrict__ wt,
                                              int* __restrict__ cnt) {
  const int i = blockIdx.x * 256 + threadIdx.x;
  if (i < F1 * 128) {
    const int n = i >> 7, k = i & 127;
    wt[i] = f2b(W[k * F1 + n]);
  }
  if (i < NN) cnt[i] = 0;
}

// ---------------- fused: MFMA GEMM (+x-cast +alpha dots) AND bucket-CSR scatter ----------------
// R9-proven structure: A staged once, B-tile LDS double-barrier loop.
__global__ __launch_bounds__(256) void gemm_scat_k(const float* __restrict__ x,
                                                   const unsigned short* __restrict__ wt,
                                                   const float* __restrict__ a_src,
                                                   const float* __restrict__ a_dst,
                                                   __hip_bfloat16* __restrict__ h,
                                                   float* __restrict__ as1,
                                                   float* __restrict__ ad1,
                                                   const int* __restrict__ ei,
                                                   int* __restrict__ cnt,
                                                   int* __restrict__ csr) {
  const int t = threadIdx.x;

  if (blockIdx.x >= GEMM_BLKS) {  // ---- scatter part (bucketed, no offsets pass) ----
    const int e = (blockIdx.x - GEMM_BLKS) * 256 + t;
    if (e >= NET) return;
    int s, d;
    if (e < NE) { s = ei[e]; d = ei[NE + e]; }
    else        { s = e - NE; d = s; }
    if ((unsigned)d >= NN || (unsigned)s >= NN) return;
    const int pos = atomicAdd(&cnt[d], 1);
    if (pos < BCAP) csr[d * BCAP + pos] = s;
    return;
  }

  // ---- GEMM part ----
  __shared__ char lds[65536];  // A: 0..32767 (128 rows x 256B), B: 32768..
  const int m0 = blockIdx.x * 128;
  const int l16 = t & 15, g16 = t >> 4;

  // stage A once (cast fp32 -> bf16 in-register)
#pragma unroll
  for (int p = 0; p < 8; ++p) {
    const int row = p * 16 + g16;
    const int gm = m0 + row;
    bf16x8 av = {};
    if (gm < NN) {
      const float4 f0 = *(const float4*)(x + (size_t)gm * 128 + l16 * 8);
      const float4 f1 = *(const float4*)(x + (size_t)gm * 128 + l16 * 8 + 4);
      av[0] = f2b(f0.x); av[1] = f2b(f0.y); av[2] = f2b(f0.z); av[3] = f2b(f0.w);
      av[4] = f2b(f1.x); av[5] = f2b(f1.y); av[6] = f2b(f1.z); av[7] = f2b(f1.w);
    }
    *(bf16x8*)(lds + SWZ(row * 256 + l16 * 16)) = av;
  }

  const int w = t >> 6;
  const int lane = t & 63;
  const int lrow = lane & 15;
  const int kgrp = (lane >> 4) * 8;
  const int rbase = (lane >> 4) * 4;

  for (int nt = 0; nt < 4; ++nt) {
    const int n0 = nt * 128;
    // stage B tile
#pragma unroll
    for (int p = 0; p < 8; ++p) {
      const int row = p * 16 + g16;
      const bf16x8 bv = *(const bf16x8*)(wt + (size_t)(n0 + row) * 128 + l16 * 8);
      *(bf16x8*)(lds + 32768 + SWZ(row * 256 + l16 * 16)) = bv;
    }
    __syncthreads();

    f32x4 acc[2][8] = {};
#pragma unroll
    for (int ks = 0; ks < 4; ++ks) {
      const int kb = (ks * 32 + kgrp) * 2;
      bf16x8 a[2], b[8];
#pragma unroll
      for (int mr = 0; mr < 2; ++mr) {
        const int row = w * 32 + mr * 16 + lrow;
        a[mr] = *(const bf16x8*)(lds + SWZ(row * 256 + kb));
      }
#pragma unroll
      for (int nr = 0; nr < 8; ++nr) {
        const int rowb = nr * 16 + lrow;
        b[nr] = *(const bf16x8*)(lds + 32768 + SWZ(rowb * 256 + kb));
      }
#pragma unroll
      for (int mr = 0; mr < 2; ++mr)
#pragma unroll
        for (int nr = 0; nr < 8; ++nr)
          acc[mr][nr] = __builtin_amdgcn_mfma_f32_16x16x32_bf16(a[mr], b[nr], acc[mr][nr], 0, 0, 0);
    }

    // epilogue for this n-tile: store h (bf16) + per-head alpha dots (fp32)
    const int head0 = n0 >> 6;
    float asv[8], adv[8];
#pragma unroll
    for (int nr = 0; nr < 8; ++nr) {
      const int cwh = (nr & 3) * 16 + lrow;
      asv[nr] = a_src[(head0 + (nr >> 2)) * 64 + cwh];
      adv[nr] = a_dst[(head0 + (nr >> 2)) * 64 + cwh];
    }
#pragma unroll
    for (int mr = 0; mr < 2; ++mr) {
#pragma unroll
      for (int r = 0; r < 4; ++r) {
        const int grow = m0 + w * 32 + mr * 16 + rbase + r;
        if (grow >= NN) continue;  // uniform within each 16-lane group
        float s0 = 0.f, s1 = 0.f, d0 = 0.f, d1 = 0.f;
#pragma unroll
        for (int nr = 0; nr < 8; ++nr) {
          const float v = acc[mr][nr][r];
          h[(size_t)grow * F1 + n0 + nr * 16 + lrow] = __float2bfloat16(v);
          if (nr < 4) { s0 = fmaf(v, asv[nr], s0); d0 = fmaf(v, adv[nr], d0); }
          else        { s1 = fmaf(v, asv[nr], s1); d1 = fmaf(v, adv[nr], d1); }
        }
#pragma unroll
        for (int m = 1; m < 16; m <<= 1) {
          s0 += __shfl_xor(s0, m); s1 += __shfl_xor(s1, m);
          d0 += __shfl_xor(d0, m); d1 += __shfl_xor(d1, m);
        }
        if (lrow == 0) {
          as1[grow * 8 + head0] = s0; as1[grow * 8 + head0 + 1] = s1;
          ad1[grow * 8 + head0] = d0; ad1[grow * 8 + head0 + 1] = d1;
        }
      }
    }
    if (nt < 3) __syncthreads();  // all waves done reading sB before restage
  }
}

// ---------------- layer-1 aggregate + ReLU + layer-2 projection fused ----------------
// R9 winner: 1 wave per node, 256-thread blocks, bucket CSR, 2x4 software pipeline.
__global__ __launch_bounds__(256) void agg1_k(const __hip_bfloat16* __restrict__ h,
                                              const float* __restrict__ as1,
                                              const float* __restrict__ ad1,
                                              const float* __restrict__ b1,
                                              const int* __restrict__ cnt,
                                              const int* __restrict__ csr,
                                              const float* __restrict__ W2,
                                              const float* __restrict__ a_s2,
                                              const float* __restrict__ a_d2,
                                              float* __restrict__ g,
                                              float* __restrict__ s2,
                                              float* __restrict__ d2) {
  const int gid = blockIdx.x * 256 + threadIdx.x;
  // node is wave-uniform; readfirstlane lets the compiler scalarize cnt/csr loads
  const int node = __builtin_amdgcn_readfirstlane(gid >> 6);
  if (node >= NN) return;
  const int lane = threadIdx.x & 63;
  const int head = lane >> 3;
  const float adv = ad1[node * 8 + head];
  int degn = cnt[node];
  degn = (degn > BCAP) ? BCAP : degn;
  const int cbase = node * BCAP;
  const unsigned short* hp = (const unsigned short*)h;
  const unsigned loff = (unsigned)(lane * 8);

  f32x2 acc2[4] = {};   // channels (2i, 2i+1) of this lane's 8
  float den = 0.f;

#define LOADC(ss, hh, aa)                                              \
  hh = *(const bf16x8*)(hp + (unsigned)(ss) * (unsigned)F1 + loff);    \
  aa = as1[(ss) * 8 + head];

#define CONSUME(hh, aa)                                                \
  {                                                                    \
    float ev = (aa) + adv;                                             \
    ev = (ev > 0.f) ? ev : ev * SLOPE;                                 \
    const float pe = __expf(ev);                                       \
    den += pe;                                                         \
    const f32x2 pv = {pe, pe};                                         \
    const unsigned* hu = (const unsigned*)&(hh);                       \
    _Pragma("unroll")                                                  \
    for (int i = 0; i < 4; ++i) {                                      \
      const unsigned u = hu[i];                                        \
      const f32x2 hv2 = {bitsf(u << 16), bitsf(u & 0xffff0000u)};      \
      acc2[i] = __builtin_elementwise_fma(pv, hv2, acc2[i]);           \
    }                                                                  \
  }

  int idx = 0;
  const bool have = (idx + 4 <= degn);
  bf16x8 hA = {}, hB = {}, hC = {}, hD = {};
  float aA = 0.f, aB = 0.f, aC = 0.f, aD = 0.f;
  if (have) {
    const int cA = csr[cbase], cB = csr[cbase + 1], cC = csr[cbase + 2], cD = csr[cbase + 3];
    LOADC(cA, hA, aA); LOADC(cB, hB, aB); LOADC(cC, hC, aC); LOADC(cD, hD, aD);
  }
  for (; idx + 8 <= degn; idx += 4) {
    // issue next chunk's loads first (overlaps with current chunk's math)
    const int nA = csr[cbase + idx + 4], nB = csr[cbase + idx + 5];
    const int nC = csr[cbase + idx + 6], nD = csr[cbase + idx + 7];
    bf16x8 xA, xB, xC, xD;
    float yA, yB, yC, yD;
    LOADC(nA, xA, yA); LOADC(nB, xB, yB); LOADC(nC, xC, yC); LOADC(nD, xD, yD);
    CONSUME(hA, aA); CONSUME(hB, aB); CONSUME(hC, aC); CONSUME(hD, aD);
    hA = xA; hB = xB; hC = xC; hD = xD;
    aA = yA; aB = yB; aC = yC; aD = yD;
  }
  if (have) {
    CONSUME(hA, aA); CONSUME(hB, aB); CONSUME(hC, aC); CONSUME(hD, aD);
    idx += 4;
  }
  for (; idx < degn; ++idx) {
    const int s = csr[cbase + idx];
    bf16x8 hv; float av;
    LOADC(s, hv, av);
    CONSUME(hv, av);
  }
#undef LOADC
#undef CONSUME

  const float inv = 1.f / (den + GEPS);
  float g0 = 0.f, g1 = 0.f;
#pragma unroll
  for (int i = 0; i < 4; ++i) {
#pragma unroll
    for (int k = 0; k < 2; ++k) {
      const int c = lane * 8 + 2 * i + k;
      const float v = fmaxf(fmaf(k ? acc2[i].y : acc2[i].x, inv, b1[c]), 0.f);
      g0 = fmaf(v, W2[2 * c + 0], g0);
      g1 = fmaf(v, W2[2 * c + 1], g1);
    }
  }
#pragma unroll
  for (int m = 1; m < 64; m <<= 1) {
    g0 += __shfl_xor(g0, m);
    g1 += __shfl_xor(g1, m);
  }
  if (lane == 0) {
    g[node * 2 + 0] = g0;
    g[node * 2 + 1] = g1;
    s2[node] = g0 * a_s2[0] + g1 * a_s2[1];
    d2[node] = g0 * a_d2[0] + g1 * a_d2[1];
  }
}

// ---------------- layer-2 aggregate (8 lanes per node) ----------------
__global__ __launch_bounds__(256) void agg2_k(const float* __restrict__ g,
                                              const float* __restrict__ s2,
                                              const float* __restrict__ d2,
                                              const float* __restrict__ b2,
                                              const int* __restrict__ cnt,
                                              const int* __restrict__ csr,
                                              float* __restrict__ out) {
  const int gid = blockIdx.x * 256 + threadIdx.x;
  const int node = gid >> 3;
  if (node >= NN) return;
  const int sub = threadIdx.x & 7;
  const float adv = d2[node];
  int degn = cnt[node];
  degn = (degn > BCAP) ? BCAP : degn;
  const int cbase = node * BCAP;
  float den = 0.f, a0 = 0.f, a1 = 0.f;
  int idx = sub;
  for (; idx + 8 < degn; idx += 16) {
    const int sA = csr[cbase + idx];
    const int sB = csr[cbase + idx + 8];
    const float2 gA = *(const float2*)(g + 2 * sA);
    const float2 gB = *(const float2*)(g + 2 * sB);
    float eA = s2[sA] + adv; eA = (eA > 0.f) ? eA : eA * SLOPE;
    float eB = s2[sB] + adv; eB = (eB > 0.f) ? eB : eB * SLOPE;
    const float pA = __expf(eA);
    const float pB = __expf(eB);
    den += pA + pB;
    a0 = fmaf(pA, gA.x, a0); a1 = fmaf(pA, gA.y, a1);
    a0 = fmaf(pB, gB.x, a0); a1 = fmaf(pB, gB.y, a1);
  }
  if (idx < degn) {
    const int s = csr[cbase + idx];
    const float2 gv = *(const float2*)(g + 2 * s);
    float ev = s2[s] + adv;
    ev = (ev > 0.f) ? ev : ev * SLOPE;
    const float p = __expf(ev);
    den += p;
    a0 = fmaf(p, gv.x, a0); a1 = fmaf(p, gv.y, a1);
  }
#pragma unroll
  for (int m = 1; m < 8; m <<= 1) {
    den += __shfl_xor(den, m);
    a0 += __shfl_xor(a0, m);
    a1 += __shfl_xor(a1, m);
  }
  if (sub == 0) {
    const float inv = 1.f / (den + GEPS);
    out[2 * node + 0] = a0 * inv + b2[0];
    out[2 * node + 1] = a1 * inv + b2[1];
  }
}

extern "C" void kernel_launch(void* const* d_in, const int* in_sizes, int n_in,
                              void* d_out, int out_size, void* d_ws, size_t ws_size,
                              hipStream_t stream) {
  (void)in_sizes; (void)n_in; (void)out_size; (void)ws_size;
  const float* x = (const float*)d_in[0];
  const int* ei = (const int*)d_in[1];
  const float* W1 = (const float*)d_in[2];
  const float* a_src1 = (const float*)d_in[3];
  const float* a_dst1 = (const float*)d_in[4];
  const float* b1 = (const float*)d_in[5];
  const float* W2 = (const float*)d_in[6];
  const float* a_src2 = (const float*)d_in[7];
  const float* a_dst2 = (const float*)d_in[8];
  const float* b2 = (const float*)d_in[9];
  float* out = (float*)d_out;

  char* ws = (char*)d_ws;
  auto alloc = [&](size_t bytes) { char* p = ws; ws += (bytes + 255) & ~(size_t)255; return p; };
  __hip_bfloat16* h = (__hip_bfloat16*)alloc((size_t)NN * F1 * 2);  // 51.2 MB
  unsigned short* wt = (unsigned short*)alloc((size_t)F1 * 128 * 2);
  float* as1 = (float*)alloc((size_t)NN * 8 * 4);
  float* ad1 = (float*)alloc((size_t)NN * 8 * 4);
  int* cnt = (int*)alloc((size_t)NN * 4);
  int* csr = (int*)alloc((size_t)NN * BCAP * 4);  // 12.8 MB buckets
  float* g = (float*)alloc((size_t)NN * 2 * 4);
  float* s2 = (float*)alloc((size_t)NN * 4);
  float* d2 = (float*)alloc((size_t)NN * 4);

  prep_k<<<(F1 * 128 + 255) / 256, 256, 0, stream>>>(W1, wt, cnt);  // also zeroes cnt
  gemm_scat_k<<<GEMM_BLKS + SCAT_BLKS, 256, 0, stream>>>(x, wt, a_src1, a_dst1, h, as1, ad1,
                                                         ei, cnt, csr);
  agg1_k<<<(NN * 64) / 256, 256, 0, stream>>>(h, as1, ad1, b1, cnt, csr, W2, a_src2, a_dst2, g, s2, d2);
  agg2_k<<<(NN * 8 + 255) / 256, 256, 0, stream>>>(g, s2, d2, b2, cnt, csr, out);
}